// Round 7
// baseline (315.221 us; speedup 1.0000x reference)
//
#include <hip/hip_runtime.h>

typedef float  f32x4 __attribute__((ext_vector_type(4)));
typedef short  s16x8 __attribute__((ext_vector_type(8)));
typedef short  s16x4 __attribute__((ext_vector_type(4)));
typedef unsigned short u16;

#define HDIM 1024
#define BATCH 32
#define SEQ 2048
#define NROWS (BATCH*SEQ)   // 65536

// k_score: 256x256 tile, BK=32, 8 waves (2M x 4N), 512 threads, 4-buf pipeline
#define BM 256
#define BN 256
#define BK 32
#define NKT (HDIM/BK)       // 32

#define GLD16(gp, lp) __builtin_amdgcn_global_load_lds( \
    (const __attribute__((address_space(1))) void*)(gp), \
    (__attribute__((address_space(3))) void*)(lp), 16, 0, 0)

#define VMCNT(n) asm volatile("s_waitcnt vmcnt(" #n ")" ::: "memory")
#define BARRIER  asm volatile("s_barrier" ::: "memory")

__device__ __forceinline__ u16 f2bf(float f){
    unsigned u = __float_as_uint(f);
    u = u + 0x7FFFu + ((u >> 16) & 1u);   // RNE
    return (u16)(u >> 16);
}

__device__ __forceinline__ float tanh_fast(float x){
    float e = __builtin_amdgcn_exp2f(x * 2.885390082f);
    return 1.0f - 2.0f * __builtin_amdgcn_rcpf(e + 1.0f);
}

// ---------------- keys fp32 -> bf16, coalesced (proven ~61 us) -------------------
__global__ __launch_bounds__(256) void k_cvt(const float* __restrict__ in,
                                             u16* __restrict__ out){
    size_t base = (size_t)blockIdx.x * 256 + threadIdx.x;   // 524288 threads
    const f32x4* ip = (const f32x4*)in;
    s16x4* op = (s16x4*)out;
#pragma unroll 4
    for (int i = 0; i < 32; ++i){
        size_t c = base + (size_t)i * 524288;
        f32x4 v = ip[c];
        s16x4 o;
        o[0] = (short)f2bf(v.x); o[1] = (short)f2bf(v.y);
        o[2] = (short)f2bf(v.z); o[3] = (short)f2bf(v.w);
        op[c] = o;
    }
}

// ---------------- W1 -> W1T (bf16, transposed) -----------------------------------
__global__ __launch_bounds__(256) void k_w1t(const float* __restrict__ W1,
                                             u16* __restrict__ W1T){
    __shared__ u16 t[64][65];
    int blk = blockIdx.x;
    int bh = blk >> 4, bd = blk & 15;
    int h0 = bh * 64, d0 = bd * 64;
    int tid = threadIdx.x;
    int lh = tid >> 4, ld = (tid & 15) * 4;
#pragma unroll
    for (int i = 0; i < 4; ++i){
        int hh = lh + i * 16;
        f32x4 v = *(const f32x4*)&W1[(size_t)(h0 + hh) * HDIM + d0 + ld];
        t[hh][ld + 0] = f2bf(v.x);
        t[hh][ld + 1] = f2bf(v.y);
        t[hh][ld + 2] = f2bf(v.z);
        t[hh][ld + 3] = f2bf(v.w);
    }
    __syncthreads();
    int wv = tid >> 6, ln = tid & 63;
#pragma unroll
    for (int i = 0; i < 16; ++i){
        int d = i * 4 + wv;
        W1T[(size_t)(d0 + d) * HDIM + h0 + ln] = t[ln][d];
    }
}

// ---------------- qproj: 512 blocks, 4 h-quarter partials + LDS reduce -----------
__global__ __launch_bounds__(256) void k_qproj(const float* __restrict__ query,
                                               const float* __restrict__ W2,
                                               float* __restrict__ qproj){
    int b = blockIdx.x >> 4, dc = blockIdx.x & 15;
    int t = threadIdx.x;
    int dl = t & 63, hq = t >> 6;
    int d = dc * 64 + dl;
    const float* q = query + (size_t)b * HDIM;
    float acc = 0.f;
#pragma unroll 8
    for (int h = hq * 256; h < hq * 256 + 256; ++h)
        acc += q[h] * W2[(size_t)h * HDIM + d];
    __shared__ float red[4][64];
    red[hq][dl] = acc;
    __syncthreads();
    if (hq == 0)
        qproj[(size_t)b * HDIM + d] = red[0][dl] + red[1][dl] + red[2][dl] + red[3][dl];
}

// ---------------- scores GEMM: 4-buf rotation, depth-3 prefetch, 1 barrier/tile --
// LDS: As[4]/Bs[4] bufs of 256x32 bf16 (16 KB each) = 128 KB total, 1 block/CU.
// Swizzle (proven 0-conflict): LDS[r][slot] = G[r][slot ^ ((r>>1)&3)].
// Per tile kt: VMCNT(8) (tiles kt+1,kt+2 stay in flight; kt landed) -> BARRIER ->
// stage tile kt+3 into slot (kt+3)&3 (holds kt-1: reads done before all waves
// crossed this barrier, by MFMA data-dependence) -> ds_read -> 32 MFMA.
// Loads get TWO full tile-periods of latency slack. Never vmcnt(0) in-loop.
__global__ __launch_bounds__(512, 2) void k_score(const u16* __restrict__ keysbf,
                                                  const u16* __restrict__ W1T,
                                                  const float* __restrict__ qproj,
                                                  const float* __restrict__ V,
                                                  float* __restrict__ spart){
    int bid = blockIdx.x;
    int lid = (bid & 7) * 128 + (bid >> 3);   // XCD swizzle; 4 nt of one mt per XCD
    int mt  = lid >> 2;           // 0..255
    int nt  = lid & 3;            // 0..3

    __shared__ u16 As[4][BM * BK];   // 64 KB
    __shared__ u16 Bs[4][BM * BK];   // 64 KB

    int tid  = threadIdx.x;
    int lane = tid & 63, wave = tid >> 6;
    int wm = wave >> 2, wn = wave & 3;
    int g  = lane >> 4, q = lane & 15;

    // staging coords: thread -> row sr (+128), pre-swizzled 16B chunk
    int sr = tid >> 2, sl = tid & 3;
    int ch = sl ^ ((sr >> 1) & 3);
    const u16* asrc = keysbf + (size_t)(mt * BM + sr) * HDIM + ch * 8;
    const u16* bsrc = W1T    + (size_t)(nt * BN + sr) * HDIM + ch * 8;
    int sdst = tid * 8;

    auto stage = [&](int buf, int kt){
        int ko = kt * BK;
        GLD16(asrc + ko,              &As[buf][sdst]);
        GLD16(asrc + ko + 128 * HDIM, &As[buf][sdst + 128 * BK]);
        GLD16(bsrc + ko,              &Bs[buf][sdst]);
        GLD16(bsrc + ko + 128 * HDIM, &Bs[buf][sdst + 128 * BK]);
    };

    // read offsets (swizzled, lane-constant across frags)
    int rslot = (g ^ ((q >> 1) & 3)) * 8;
    int aoff = (wm * 128 + q) * BK + rslot;       // + m*16*BK per m-frag
    int boff = (wn * 64 + q) * BK + rslot;        // + n*16*BK per n-frag

    f32x4 acc[8][4];
#pragma unroll
    for (int m = 0; m < 8; ++m)
#pragma unroll
        for (int n = 0; n < 4; ++n) acc[m][n] = 0.f;

    // prologue: stage tiles 0,1,2 (12 loads)
    stage(0, 0);
    stage(1, 1);
    stage(2, 2);

    for (int kt = 0; kt < NKT; ++kt){
        int c = kt & 3;
        int tn = (kt + 3 < NKT) ? kt + 3 : NKT - 1;   // dummy re-stage at tail

        VMCNT(8);      // tile kt fully landed; kt+1,kt+2 (8 loads) stay in flight
        BARRIER;       // all waves: slot (kt+3)&3's old reads done; tile kt visible
        stage((kt + 3) & 3, tn);

        s16x8 af[8], bq[4];
#pragma unroll
        for (int m = 0; m < 8; ++m) af[m] = *(const s16x8*)&As[c][aoff + m * 16 * BK];
#pragma unroll
        for (int n = 0; n < 4; ++n) bq[n] = *(const s16x8*)&Bs[c][boff + n * 512];
        __builtin_amdgcn_s_setprio(1);
#pragma unroll
        for (int m = 0; m < 8; ++m)
#pragma unroll
            for (int n = 0; n < 4; ++n)
                acc[m][n] = __builtin_amdgcn_mfma_f32_16x16x32_bf16(af[m], bq[n], acc[m][n], 0, 0, 0);
        __builtin_amdgcn_s_setprio(0);
    }
    VMCNT(0);   // drain dummy stages before LDS dealloc

    // ---- epilogue: spart[R][nt*4+wn] over this wave's 64 d-cols ----
    int b_idx = mt >> 3;
    float Vn[4], Qn[4];
#pragma unroll
    for (int n = 0; n < 4; ++n){
        int D = nt * BN + wn * 64 + n * 16 + q;
        Vn[n] = V[D];
        Qn[n] = qproj[(size_t)b_idx * HDIM + D];
    }
#pragma unroll
    for (int m = 0; m < 8; ++m){
#pragma unroll
        for (int r = 0; r < 4; ++r){
            float s = 0.f;
#pragma unroll
            for (int n = 0; n < 4; ++n){
                float x = acc[m][n][r] + Qn[n];
                s += Vn[n] * tanh_fast(x);
            }
            s += __shfl_xor(s, 1);
            s += __shfl_xor(s, 2);
            s += __shfl_xor(s, 4);
            s += __shfl_xor(s, 8);
            if (q == 0){
                int R = mt * BM + wm * 128 + m * 16 + g * 4 + r;
                spart[(size_t)R * 16 + nt * 4 + wn] = s;
            }
        }
    }
}

// ---------------- softmax over S per batch ---------------------------------------
__global__ __launch_bounds__(256) void k_softmax(const float* __restrict__ spart,
                                                 const int* __restrict__ mask,
                                                 float* __restrict__ attn){
    int b = blockIdx.x;
    int tid = threadIdx.x;
    int lane = tid & 63, wv = tid >> 6;
    __shared__ float redmx[4];
    __shared__ float redsm[4];

    float sc[8];
#pragma unroll
    for (int i = 0; i < 8; ++i){
        int s = i * 256 + tid;
        const f32x4* p = (const f32x4*)&spart[(size_t)(b * SEQ + s) * 16];
        f32x4 v0 = p[0], v1 = p[1], v2 = p[2], v3 = p[3];
        float sum = (v0.x + v0.y + v0.z + v0.w) + (v1.x + v1.y + v1.z + v1.w)
                  + (v2.x + v2.y + v2.z + v2.w) + (v3.x + v3.y + v3.z + v3.w);
        sc[i] = (mask[b * SEQ + s] == 0) ? -1e9f : sum;
    }
    float mx = sc[0];
#pragma unroll
    for (int i = 1; i < 8; ++i) mx = fmaxf(mx, sc[i]);
#pragma unroll
    for (int o = 32; o >= 1; o >>= 1) mx = fmaxf(mx, __shfl_xor(mx, o));
    if (lane == 0) redmx[wv] = mx;
    __syncthreads();
    mx = fmaxf(fmaxf(redmx[0], redmx[1]), fmaxf(redmx[2], redmx[3]));

    float ex[8], ssum = 0.f;
#pragma unroll
    for (int i = 0; i < 8; ++i){
        ex[i] = __builtin_amdgcn_exp2f((sc[i] - mx) * 1.4426950408889634f);
        ssum += ex[i];
    }
#pragma unroll
    for (int o = 32; o >= 1; o >>= 1) ssum += __shfl_xor(ssum, o);
    if (lane == 0) redsm[wv] = ssum;
    __syncthreads();
    ssum = redsm[0] + redsm[1] + redsm[2] + redsm[3];
    float inv = 1.0f / ssum;
#pragma unroll
    for (int i = 0; i < 8; ++i)
        attn[(size_t)b * SEQ + i * 256 + tid] = ex[i] * inv;
}

// ---------------- context partials from bf16 keys: cpart[b][32][h] ---------------
__global__ __launch_bounds__(256) void k_ctxpart(const u16* __restrict__ keysbf,
                                                 const float* __restrict__ attn,
                                                 float* __restrict__ cpart){
    int blk = blockIdx.x;                 // 1024 blocks
    int b = blk >> 5, scn = blk & 31;     // 64 rows each
    int t = threadIdx.x;
    f32x4 acc = 0.f;
    const s16x4* kp = (const s16x4*)(keysbf + (size_t)(b * SEQ + scn * 64) * HDIM) + t;
    const float* ap = attn + (size_t)b * SEQ + scn * 64;
#pragma unroll 8
    for (int s = 0; s < 64; ++s){
        float a = ap[s];
        s16x4 kv = kp[(size_t)s * 256];
        f32x4 kf;
        kf.x = __uint_as_float((unsigned)(unsigned short)kv[0] << 16);
        kf.y = __uint_as_float((unsigned)(unsigned short)kv[1] << 16);
        kf.z = __uint_as_float((unsigned)(unsigned short)kv[2] << 16);
        kf.w = __uint_as_float((unsigned)(unsigned short)kv[3] << 16);
        acc += a * kf;
    }
    *(f32x4*)&cpart[(size_t)(b * 32 + scn) * HDIM + t * 4] = acc;
}

__global__ __launch_bounds__(256) void k_ctxred(const float* __restrict__ cpart,
                                                float* __restrict__ ctx){
    int idx = blockIdx.x * 256 + threadIdx.x;   // 128 blocks
    int b = idx >> 10, h = idx & 1023;
    float s = 0.f;
#pragma unroll
    for (int sc = 0; sc < 32; ++sc)
        s += cpart[(size_t)(b * 32 + sc) * HDIM + h];
    ctx[idx] = s;
}

// ---------------- launch ---------------------------------------------------------
extern "C" void kernel_launch(void* const* d_in, const int* in_sizes, int n_in,
                              void* d_out, int out_size, void* d_ws, size_t ws_size,
                              hipStream_t stream){
    (void)in_sizes; (void)n_in; (void)out_size; (void)ws_size;
    const float* query = (const float*)d_in[0];
    const float* keys  = (const float*)d_in[1];
    const int*   mask  = (const int*)d_in[2];
    const float* W1    = (const float*)d_in[3];
    const float* W2    = (const float*)d_in[4];
    const float* V     = (const float*)d_in[5];

    float* ctx_out  = (float*)d_out;            // [32][1024]
    float* attn_out = ctx_out + BATCH * HDIM;   // [32][2048]

    char* ws = (char*)d_ws;
    u16*   W1T   = (u16*)ws;                                   // 2 MB
    float* qproj = (float*)(ws + (2u << 20));                  // 128 KB
    float* spart = (float*)(ws + (2u << 20) + (128u << 10));   // 4 MB
    float* cpart = spart;   // ctxpart partials reuse spart (dead after softmax)
    u16*   keysbf= (u16*)(ws + (9u << 20));                    // 128 MB

    k_w1t    <<<dim3(256),  dim3(256), 0, stream>>>(W1, W1T);
    k_qproj  <<<dim3(512),  dim3(256), 0, stream>>>(query, W2, qproj);
    k_cvt    <<<dim3(2048), dim3(256), 0, stream>>>(keys, keysbf);
    k_score  <<<dim3(1024), dim3(512), 0, stream>>>(keysbf, W1T, qproj, V, spart);
    k_softmax<<<dim3(32),   dim3(256), 0, stream>>>(spart, mask, attn_out);
    k_ctxpart<<<dim3(1024), dim3(256), 0, stream>>>(keysbf, attn_out, cpart);
    k_ctxred <<<dim3(128),  dim3(256), 0, stream>>>(cpart, ctx_out);
}

// Round 8
// 307.879 us; speedup vs baseline: 1.0238x; 1.0238x over previous
//
#include <hip/hip_runtime.h>

typedef float  f32x4 __attribute__((ext_vector_type(4)));
typedef short  s16x8 __attribute__((ext_vector_type(8)));
typedef short  s16x4 __attribute__((ext_vector_type(4)));
typedef unsigned short u16;

#define HDIM 1024
#define BATCH 32
#define SEQ 2048
#define NROWS (BATCH*SEQ)   // 65536

// k_score geometry: 256x256 tile, BK=64, 8 waves (2M x 4N), 512 threads, 1 blk/CU
#define NTILES 16           // K / 64
#define PLANE 4096          // elems per LDS plane: 128 rows x 32 (64B rows)

#define GLD16(gp, lp) __builtin_amdgcn_global_load_lds( \
    (const __attribute__((address_space(1))) void*)(gp), \
    (__attribute__((address_space(3))) void*)(lp), 16, 0, 0)

#define VMCNT(n) asm volatile("s_waitcnt vmcnt(" #n ")" ::: "memory")
#define LGKM0    asm volatile("s_waitcnt lgkmcnt(0)" ::: "memory")
#define BARRIER  asm volatile("s_barrier" ::: "memory")

__device__ __forceinline__ u16 f2bf(float f){
    unsigned u = __float_as_uint(f);
    u = u + 0x7FFFu + ((u >> 16) & 1u);   // RNE
    return (u16)(u >> 16);
}

__device__ __forceinline__ float tanh_fast(float x){
    float e = __builtin_amdgcn_exp2f(x * 2.885390082f);
    return 1.0f - 2.0f * __builtin_amdgcn_rcpf(e + 1.0f);
}

// ---------------- keys fp32 -> bf16, coalesced (proven ~61 us) -------------------
__global__ __launch_bounds__(256) void k_cvt(const float* __restrict__ in,
                                             u16* __restrict__ out){
    size_t base = (size_t)blockIdx.x * 256 + threadIdx.x;   // 524288 threads
    const f32x4* ip = (const f32x4*)in;
    s16x4* op = (s16x4*)out;
#pragma unroll 4
    for (int i = 0; i < 32; ++i){
        size_t c = base + (size_t)i * 524288;
        f32x4 v = ip[c];
        s16x4 o;
        o[0] = (short)f2bf(v.x); o[1] = (short)f2bf(v.y);
        o[2] = (short)f2bf(v.z); o[3] = (short)f2bf(v.w);
        op[c] = o;
    }
}

// ---------------- W1 -> W1T (bf16, transposed) -----------------------------------
__global__ __launch_bounds__(256) void k_w1t(const float* __restrict__ W1,
                                             u16* __restrict__ W1T){
    __shared__ u16 t[64][65];
    int blk = blockIdx.x;
    int bh = blk >> 4, bd = blk & 15;
    int h0 = bh * 64, d0 = bd * 64;
    int tid = threadIdx.x;
    int lh = tid >> 4, ld = (tid & 15) * 4;
#pragma unroll
    for (int i = 0; i < 4; ++i){
        int hh = lh + i * 16;
        f32x4 v = *(const f32x4*)&W1[(size_t)(h0 + hh) * HDIM + d0 + ld];
        t[hh][ld + 0] = f2bf(v.x);
        t[hh][ld + 1] = f2bf(v.y);
        t[hh][ld + 2] = f2bf(v.z);
        t[hh][ld + 3] = f2bf(v.w);
    }
    __syncthreads();
    int wv = tid >> 6, ln = tid & 63;
#pragma unroll
    for (int i = 0; i < 16; ++i){
        int d = i * 4 + wv;
        W1T[(size_t)(d0 + d) * HDIM + h0 + ln] = t[ln][d];
    }
}

// ---------------- qproj: 512 blocks, 4 h-quarter partials + LDS reduce -----------
__global__ __launch_bounds__(256) void k_qproj(const float* __restrict__ query,
                                               const float* __restrict__ W2,
                                               float* __restrict__ qproj){
    int b = blockIdx.x >> 4, dc = blockIdx.x & 15;
    int t = threadIdx.x;
    int dl = t & 63, hq = t >> 6;
    int d = dc * 64 + dl;
    const float* q = query + (size_t)b * HDIM;
    float acc = 0.f;
#pragma unroll 8
    for (int h = hq * 256; h < hq * 256 + 256; ++h)
        acc += q[h] * W2[(size_t)h * HDIM + d];
    __shared__ float red[4][64];
    red[hq][dl] = acc;
    __syncthreads();
    if (hq == 0)
        qproj[(size_t)b * HDIM + d] = red[0][dl] + red[1][dl] + red[2][dl] + red[3][dl];
}

// ---------------- m201-faithful 8-phase 256^2 scores GEMM ------------------------
// LDS planes: [buf(2)][half(2)][ks(2)] of 128 rows x 32 elems (64B rows), 128 KB.
// Swizzle (proven 0-conflict, refcheck'd R4): LDS[r][slot] = G[r][slot^((r>>1)&3)].
// Per K-tile (BK=64), 4 phases; each phase:
//   {ds_read subtile || stage 1 half-tile} -> BARRIER -> lgkmcnt(0) ->
//   setprio(1) -> 16 MFMA -> setprio(0) -> [VMCNT(4) at phases P1,P3] -> BARRIER
// NO sched_barrier (m141 poison). vmcnt never 0 in-loop. Boundary safety: the
// VMCNT(4)+BARRIER pair at P1/P3 makes the staged half-tiles chip-wide visible
// BEFORE any wave issues the ds_reads that consume them (P2 / next-tile P0).
__global__ __launch_bounds__(512, 2) void k_score(const u16* __restrict__ keysbf,
                                                  const u16* __restrict__ W1T,
                                                  const float* __restrict__ qproj,
                                                  const float* __restrict__ V,
                                                  float* __restrict__ spart){
    int bid = blockIdx.x;
    int lid = (bid & 7) * 128 + (bid >> 3);   // XCD swizzle; 4 nt of one mt per XCD
    int mt  = lid >> 2;           // 0..255
    int nt  = lid & 3;            // 0..3

    __shared__ u16 As[8 * PLANE];   // 64 KB
    __shared__ u16 Bs[8 * PLANE];   // 64 KB

    int tid  = threadIdx.x;
    int lane = tid & 63, wave = tid >> 6;
    int wm = wave >> 2, wn = wave & 3;
    int g  = lane >> 4, q = lane & 15;

    // staging coords (pre-swizzled global source, linear LDS dest)
    int sr = tid >> 2, sl = tid & 3;
    int ch = sl ^ ((sr >> 1) & 3);
    const u16* abase = keysbf + (size_t)(mt * 256 + sr) * HDIM + ch * 8;
    const u16* bbase = W1T    + (size_t)(nt * 256 + sr) * HDIM + ch * 8;
    int sdst = tid * 8;

    auto stageA = [&](int buf, int t, int ks){
        int ko = t * 64 + ks * 32;
        GLD16(abase + ko,              &As[((buf << 2) | ks) * PLANE + sdst]);
        GLD16(abase + ko + 128 * HDIM, &As[((buf << 2) | 2 | ks) * PLANE + sdst]);
    };
    auto stageB = [&](int buf, int t, int ks){
        int ko = t * 64 + ks * 32;
        GLD16(bbase + ko,              &Bs[((buf << 2) | ks) * PLANE + sdst]);
        GLD16(bbase + ko + 128 * HDIM, &Bs[((buf << 2) | 2 | ks) * PLANE + sdst]);
    };

    // read offsets (swizzled, lane-constant across frags; refcheck'd R4)
    int rslot = (g ^ ((q >> 1) & 3)) * 8;
    int arow  = q * 32 + rslot;                        // + m*512
    int brow  = ((wn & 1) * 64 + q) * 32 + rslot;      // + n*512

    f32x4 acc[8][4];
#pragma unroll
    for (int m = 0; m < 8; ++m)
#pragma unroll
        for (int n = 0; n < 4; ++n) acc[m][n] = 0.f;

    // prologue: stage tile 0 (4 half-tile units, 8 loads); ks0 landed + barrier
    stageA(0, 0, 0); stageB(0, 0, 0); stageA(0, 0, 1); stageB(0, 0, 1);
    VMCNT(4);       // A-ks0, B-ks0 landed; ks1 units stay in flight
    BARRIER;

    for (int t = 0; t < NTILES; ++t){
        int c = t & 1, nb = c ^ 1;
        int tn = (t + 1 < NTILES) ? t + 1 : NTILES - 1;   // dummy re-stage at tail
        const u16* Ap0 = &As[((c << 2) | (wm << 1)) * PLANE];
        const u16* Bp0 = &Bs[((c << 2) | ((wn >> 1) << 1)) * PLANE];
        const u16* Ap1 = Ap0 + PLANE;
        const u16* Bp1 = Bp0 + PLANE;
        s16x8 af[4], bq[4];

        // ---- P0: ks0, m0-3 (8 ds_read) ----
#pragma unroll
        for (int m = 0; m < 4; ++m) af[m] = *(const s16x8*)&Ap0[arow + m * 512];
#pragma unroll
        for (int n = 0; n < 4; ++n) bq[n] = *(const s16x8*)&Bp0[brow + n * 512];
        stageA(nb, tn, 0);
        BARRIER;
        LGKM0;
        __builtin_amdgcn_s_setprio(1);
#pragma unroll
        for (int m = 0; m < 4; ++m)
#pragma unroll
            for (int n = 0; n < 4; ++n)
                acc[m][n] = __builtin_amdgcn_mfma_f32_16x16x32_bf16(af[m], bq[n], acc[m][n], 0, 0, 0);
        __builtin_amdgcn_s_setprio(0);
        BARRIER;

        // ---- P1: ks0, m4-7 (4 ds_read; bq reused) ----
#pragma unroll
        for (int m = 0; m < 4; ++m) af[m] = *(const s16x8*)&Ap0[arow + (m + 4) * 512];
        stageB(nb, tn, 0);
        BARRIER;
        LGKM0;
        __builtin_amdgcn_s_setprio(1);
#pragma unroll
        for (int m = 0; m < 4; ++m)
#pragma unroll
            for (int n = 0; n < 4; ++n)
                acc[m + 4][n] = __builtin_amdgcn_mfma_f32_16x16x32_bf16(af[m], bq[n], acc[m + 4][n], 0, 0, 0);
        __builtin_amdgcn_s_setprio(0);
        VMCNT(4);      // ks1 of tile t landed (oldest 4 of 8 outstanding)
        BARRIER;

        // ---- P2: ks1, m0-3 (8 ds_read) ----
#pragma unroll
        for (int m = 0; m < 4; ++m) af[m] = *(const s16x8*)&Ap1[arow + m * 512];
#pragma unroll
        for (int n = 0; n < 4; ++n) bq[n] = *(const s16x8*)&Bp1[brow + n * 512];
        stageA(nb, tn, 1);
        BARRIER;
        LGKM0;
        __builtin_amdgcn_s_setprio(1);
#pragma unroll
        for (int m = 0; m < 4; ++m)
#pragma unroll
            for (int n = 0; n < 4; ++n)
                acc[m][n] = __builtin_amdgcn_mfma_f32_16x16x32_bf16(af[m], bq[n], acc[m][n], 0, 0, 0);
        __builtin_amdgcn_s_setprio(0);
        BARRIER;

        // ---- P3: ks1, m4-7 (4 ds_read; bq reused) ----
#pragma unroll
        for (int m = 0; m < 4; ++m) af[m] = *(const s16x8*)&Ap1[arow + (m + 4) * 512];
        stageB(nb, tn, 1);
        BARRIER;
        LGKM0;
        __builtin_amdgcn_s_setprio(1);
#pragma unroll
        for (int m = 0; m < 4; ++m)
#pragma unroll
            for (int n = 0; n < 4; ++n)
                acc[m + 4][n] = __builtin_amdgcn_mfma_f32_16x16x32_bf16(af[m], bq[n], acc[m + 4][n], 0, 0, 0);
        __builtin_amdgcn_s_setprio(0);
        VMCNT(4);      // ks0 of tile t+1 landed
        BARRIER;
    }
    VMCNT(0);   // drain dummy stages before LDS dealloc

    // ---- epilogue: spart[R][nt*4+wn] over this wave's 64 d-cols ----
    int b_idx = mt >> 3;
    float Vn[4], Qn[4];
#pragma unroll
    for (int n = 0; n < 4; ++n){
        int D = nt * 256 + wn * 64 + n * 16 + q;
        Vn[n] = V[D];
        Qn[n] = qproj[(size_t)b_idx * HDIM + D];
    }
#pragma unroll
    for (int m = 0; m < 8; ++m){
#pragma unroll
        for (int r = 0; r < 4; ++r){
            float s = 0.f;
#pragma unroll
            for (int n = 0; n < 4; ++n){
                float x = acc[m][n][r] + Qn[n];
                s += Vn[n] * tanh_fast(x);
            }
            s += __shfl_xor(s, 1);
            s += __shfl_xor(s, 2);
            s += __shfl_xor(s, 4);
            s += __shfl_xor(s, 8);
            if (q == 0){
                int R = mt * 256 + wm * 128 + m * 16 + g * 4 + r;
                spart[(size_t)R * 16 + nt * 4 + wn] = s;
            }
        }
    }
}

// ---------------- softmax over S per batch ---------------------------------------
__global__ __launch_bounds__(256) void k_softmax(const float* __restrict__ spart,
                                                 const int* __restrict__ mask,
                                                 float* __restrict__ attn){
    int b = blockIdx.x;
    int tid = threadIdx.x;
    int lane = tid & 63, wv = tid >> 6;
    __shared__ float redmx[4];
    __shared__ float redsm[4];

    float sc[8];
#pragma unroll
    for (int i = 0; i < 8; ++i){
        int s = i * 256 + tid;
        const f32x4* p = (const f32x4*)&spart[(size_t)(b * SEQ + s) * 16];
        f32x4 v0 = p[0], v1 = p[1], v2 = p[2], v3 = p[3];
        float sum = (v0.x + v0.y + v0.z + v0.w) + (v1.x + v1.y + v1.z + v1.w)
                  + (v2.x + v2.y + v2.z + v2.w) + (v3.x + v3.y + v3.z + v3.w);
        sc[i] = (mask[b * SEQ + s] == 0) ? -1e9f : sum;
    }
    float mx = sc[0];
#pragma unroll
    for (int i = 1; i < 8; ++i) mx = fmaxf(mx, sc[i]);
#pragma unroll
    for (int o = 32; o >= 1; o >>= 1) mx = fmaxf(mx, __shfl_xor(mx, o));
    if (lane == 0) redmx[wv] = mx;
    __syncthreads();
    mx = fmaxf(fmaxf(redmx[0], redmx[1]), fmaxf(redmx[2], redmx[3]));

    float ex[8], ssum = 0.f;
#pragma unroll
    for (int i = 0; i < 8; ++i){
        ex[i] = __builtin_amdgcn_exp2f((sc[i] - mx) * 1.4426950408889634f);
        ssum += ex[i];
    }
#pragma unroll
    for (int o = 32; o >= 1; o >>= 1) ssum += __shfl_xor(ssum, o);
    if (lane == 0) redsm[wv] = ssum;
    __syncthreads();
    ssum = redsm[0] + redsm[1] + redsm[2] + redsm[3];
    float inv = 1.0f / ssum;
#pragma unroll
    for (int i = 0; i < 8; ++i)
        attn[(size_t)b * SEQ + i * 256 + tid] = ex[i] * inv;
}

// ---------------- context partials from bf16 keys: cpart[b][32][h] ---------------
__global__ __launch_bounds__(256) void k_ctxpart(const u16* __restrict__ keysbf,
                                                 const float* __restrict__ attn,
                                                 float* __restrict__ cpart){
    int blk = blockIdx.x;                 // 1024 blocks
    int b = blk >> 5, scn = blk & 31;     // 64 rows each
    int t = threadIdx.x;
    f32x4 acc = 0.f;
    const s16x4* kp = (const s16x4*)(keysbf + (size_t)(b * SEQ + scn * 64) * HDIM) + t;
    const float* ap = attn + (size_t)b * SEQ + scn * 64;
#pragma unroll 8
    for (int s = 0; s < 64; ++s){
        float a = ap[s];
        s16x4 kv = kp[(size_t)s * 256];
        f32x4 kf;
        kf.x = __uint_as_float((unsigned)(unsigned short)kv[0] << 16);
        kf.y = __uint_as_float((unsigned)(unsigned short)kv[1] << 16);
        kf.z = __uint_as_float((unsigned)(unsigned short)kv[2] << 16);
        kf.w = __uint_as_float((unsigned)(unsigned short)kv[3] << 16);
        acc += a * kf;
    }
    *(f32x4*)&cpart[(size_t)(b * 32 + scn) * HDIM + t * 4] = acc;
}

__global__ __launch_bounds__(256) void k_ctxred(const float* __restrict__ cpart,
                                                float* __restrict__ ctx){
    int idx = blockIdx.x * 256 + threadIdx.x;   // 128 blocks
    int b = idx >> 10, h = idx & 1023;
    float s = 0.f;
#pragma unroll
    for (int sc = 0; sc < 32; ++sc)
        s += cpart[(size_t)(b * 32 + sc) * HDIM + h];
    ctx[idx] = s;
}

// ---------------- launch ---------------------------------------------------------
extern "C" void kernel_launch(void* const* d_in, const int* in_sizes, int n_in,
                              void* d_out, int out_size, void* d_ws, size_t ws_size,
                              hipStream_t stream){
    (void)in_sizes; (void)n_in; (void)out_size; (void)ws_size;
    const float* query = (const float*)d_in[0];
    const float* keys  = (const float*)d_in[1];
    const int*   mask  = (const int*)d_in[2];
    const float* W1    = (const float*)d_in[3];
    const float* W2    = (const float*)d_in[4];
    const float* V     = (const float*)d_in[5];

    float* ctx_out  = (float*)d_out;            // [32][1024]
    float* attn_out = ctx_out + BATCH * HDIM;   // [32][2048]

    char* ws = (char*)d_ws;
    u16*   W1T   = (u16*)ws;                                   // 2 MB
    float* qproj = (float*)(ws + (2u << 20));                  // 128 KB
    float* spart = (float*)(ws + (2u << 20) + (128u << 10));   // 4 MB
    float* cpart = spart;   // ctxpart partials reuse spart (dead after softmax)
    u16*   keysbf= (u16*)(ws + (9u << 20));                    // 128 MB

    k_w1t    <<<dim3(256),  dim3(256), 0, stream>>>(W1, W1T);
    k_qproj  <<<dim3(512),  dim3(256), 0, stream>>>(query, W2, qproj);
    k_cvt    <<<dim3(2048), dim3(256), 0, stream>>>(keys, keysbf);
    k_score  <<<dim3(1024), dim3(512), 0, stream>>>(keysbf, W1T, qproj, V, spart);
    k_softmax<<<dim3(32),   dim3(256), 0, stream>>>(spart, mask, attn_out);
    k_ctxpart<<<dim3(1024), dim3(256), 0, stream>>>(keysbf, attn_out, cpart);
    k_ctxred <<<dim3(128),  dim3(256), 0, stream>>>(cpart, ctx_out);
}

// Round 9
// 297.147 us; speedup vs baseline: 1.0608x; 1.0361x over previous
//
#include <hip/hip_runtime.h>

typedef float  f32x4 __attribute__((ext_vector_type(4)));
typedef short  s16x8 __attribute__((ext_vector_type(8)));
typedef short  s16x4 __attribute__((ext_vector_type(4)));
typedef unsigned short u16;

#define HDIM 1024
#define BATCH 32
#define SEQ 2048
#define NROWS (BATCH*SEQ)   // 65536

// k_score: 256x256 tile, BK=32, 8 waves (2M x 4N), 512 threads
// A (keys bf16) double-buffered in LDS (32 KB); B (W1) fragment-packed in W1F,
// loaded straight from L2 into registers, double-buffered one tile ahead.
#define BK 32
#define NKT (HDIM/BK)       // 32

#define GLD16(gp, lp) __builtin_amdgcn_global_load_lds( \
    (const __attribute__((address_space(1))) void*)(gp), \
    (__attribute__((address_space(3))) void*)(lp), 16, 0, 0)

#define VMCNT(n) asm volatile("s_waitcnt vmcnt(" #n ")" ::: "memory")
#define BARRIER  asm volatile("s_barrier" ::: "memory")

__device__ __forceinline__ u16 f2bf(float f){
    unsigned u = __float_as_uint(f);
    u = u + 0x7FFFu + ((u >> 16) & 1u);   // RNE
    return (u16)(u >> 16);
}

__device__ __forceinline__ float tanh_fast(float x){
    float e = __builtin_amdgcn_exp2f(x * 2.885390082f);
    return 1.0f - 2.0f * __builtin_amdgcn_rcpf(e + 1.0f);
}

// ---------------- keys fp32 -> bf16, coalesced (~61 us, HBM floor) ---------------
__global__ __launch_bounds__(256) void k_cvt(const float* __restrict__ in,
                                             u16* __restrict__ out){
    size_t base = (size_t)blockIdx.x * 256 + threadIdx.x;   // 524288 threads
    const f32x4* ip = (const f32x4*)in;
    s16x4* op = (s16x4*)out;
#pragma unroll 4
    for (int i = 0; i < 32; ++i){
        size_t c = base + (size_t)i * 524288;
        f32x4 v = ip[c];
        s16x4 o;
        o[0] = (short)f2bf(v.x); o[1] = (short)f2bf(v.y);
        o[2] = (short)f2bf(v.z); o[3] = (short)f2bf(v.w);
        op[c] = o;
    }
}

// ---------------- W1 -> W1T (bf16, transposed) -----------------------------------
__global__ __launch_bounds__(256) void k_w1t(const float* __restrict__ W1,
                                             u16* __restrict__ W1T){
    __shared__ u16 t[64][65];
    int blk = blockIdx.x;
    int bh = blk >> 4, bd = blk & 15;
    int h0 = bh * 64, d0 = bd * 64;
    int tid = threadIdx.x;
    int lh = tid >> 4, ld = (tid & 15) * 4;
#pragma unroll
    for (int i = 0; i < 4; ++i){
        int hh = lh + i * 16;
        f32x4 v = *(const f32x4*)&W1[(size_t)(h0 + hh) * HDIM + d0 + ld];
        t[hh][ld + 0] = f2bf(v.x);
        t[hh][ld + 1] = f2bf(v.y);
        t[hh][ld + 2] = f2bf(v.z);
        t[hh][ld + 3] = f2bf(v.w);
    }
    __syncthreads();
    int wv = tid >> 6, ln = tid & 63;
#pragma unroll
    for (int i = 0; i < 16; ++i){
        int d = i * 4 + wv;
        W1T[(size_t)(d0 + d) * HDIM + h0 + ln] = t[ln][d];
    }
}

// ---------------- W1T -> W1F (MFMA-fragment order) -------------------------------
// Chunk (nt,kt,wn,n): 64 lanes x 16B; lane l=(g*16+q) holds W1[kt*32+g*8 .. +8][d],
// d = nt*256+wn*64+n*16+q. k_score loads bq[n] as ONE coalesced b128 per lane.
__global__ __launch_bounds__(256) void k_w1f(const u16* __restrict__ W1T,
                                             u16* __restrict__ W1F){
    int idx = blockIdx.x * 256 + threadIdx.x;    // 512 blocks -> 131072 chunks*lanes
    int q  = idx & 15;
    int gg = (idx >> 4) & 3;
    int n  = (idx >> 6) & 3;
    int wn = (idx >> 8) & 3;
    int kt = (idx >> 10) & 31;
    int nt = (idx >> 15) & 3;
    int d  = nt * 256 + wn * 64 + n * 16 + q;
    int h0 = kt * 32 + gg * 8;
    s16x8 v = *(const s16x8*)&W1T[(size_t)d * HDIM + h0];
    *(s16x8*)&W1F[(size_t)idx * 8] = v;
}

// ---------------- qproj: 512 blocks, 4 h-quarter partials + LDS reduce -----------
__global__ __launch_bounds__(256) void k_qproj(const float* __restrict__ query,
                                               const float* __restrict__ W2,
                                               float* __restrict__ qproj){
    int b = blockIdx.x >> 4, dc = blockIdx.x & 15;
    int t = threadIdx.x;
    int dl = t & 63, hq = t >> 6;
    int d = dc * 64 + dl;
    const float* q = query + (size_t)b * HDIM;
    float acc = 0.f;
#pragma unroll 8
    for (int h = hq * 256; h < hq * 256 + 256; ++h)
        acc += q[h] * W2[(size_t)h * HDIM + d];
    __shared__ float red[4][64];
    red[hq][dl] = acc;
    __syncthreads();
    if (hq == 0)
        qproj[(size_t)b * HDIM + d] = red[0][dl] + red[1][dl] + red[2][dl] + red[3][dl];
}

// ---------------- scores GEMM: A-only LDS, B-from-L2 reg double-buffer -----------
// Per tile-pair (even kE=2j / odd kO=2j+1), each half-body:
//   {4 bq global loads (next tile's B) || 8 ds_read A || 32 MFMA}
//   VMCNT(4)  -> the A-stage for the NEXT tile has landed (FIFO-audited)
//   BARRIER   -> publishes it chip-wide; all reads of this buf are done
//   stageA    -> overwrite this buf with tile+2 (2 gload_lds)
// One barrier per tile; vmcnt never 0 in-loop; bq consumed >=1 body after issue.
__global__ __launch_bounds__(512, 2) void k_score(const u16* __restrict__ keysbf,
                                                  const u16* __restrict__ W1F,
                                                  const float* __restrict__ qproj,
                                                  const float* __restrict__ V,
                                                  float* __restrict__ spart){
    int bid = blockIdx.x;
    int lid = (bid & 7) * 128 + (bid >> 3);   // XCD swizzle; 4 nt of one mt per XCD
    int mt  = lid >> 2;           // 0..255
    int nt  = lid & 3;            // 0..3

    __shared__ u16 As[2][256 * BK];   // 16 KB per buf, 32 KB total

    int tid  = threadIdx.x;
    int lane = tid & 63, wave = tid >> 6;
    int wm = wave >> 2, wn = wave & 3;
    int g  = lane >> 4, q = lane & 15;

    // A staging (pre-swizzled global source, linear LDS dest) — proven 0-conflict
    int sr = tid >> 2, sl = tid & 3;
    int ch = sl ^ ((sr >> 1) & 3);
    const u16* asrc = keysbf + (size_t)(mt * 256 + sr) * HDIM + ch * 8;
    int sdst = tid * 8;

    auto stageA = [&](int buf, int kt){
        int ko = kt * BK;
        GLD16(asrc + ko,              &As[buf][sdst]);
        GLD16(asrc + ko + 128 * HDIM, &As[buf][sdst + 128 * BK]);
    };

    // B fragment base: chunk(nt,kt,wn,n) at elems (nt*32+kt)*8192 + (wn*4+n)*512
    const u16* bfr = W1F + (size_t)nt * 32 * 8192 + (wn * 4) * 512 + lane * 8;

    // A read offsets (swizzled, lane-constant)
    int rslot = (g ^ ((q >> 1) & 3)) * 8;
    int aoff  = (wm * 128 + q) * BK + rslot;      // + m*512 per m-frag

    f32x4 acc[8][4];
#pragma unroll
    for (int m = 0; m < 8; ++m)
#pragma unroll
        for (int n = 0; n < 4; ++n) acc[m][n] = 0.f;

    s16x8 bqE[4], bqO[4];

    // prologue: stage tiles 0,1 (4 loads); load bqE(tile 0)
    stageA(0, 0);
    stageA(1, 1);
#pragma unroll
    for (int n = 0; n < 4; ++n) bqE[n] = *(const s16x8*)(bfr + n * 512);
    VMCNT(6);       // tile 0 A-stage landed (oldest 2); tile 1 + bqE in flight
    BARRIER;

    for (int j = 0; j < 16; ++j){
        int kO   = 2 * j + 1;                       // odd tile of this pair
        int kEn  = (2 * j + 2 < NKT) ? 2 * j + 2 : NKT - 1;  // next even (dummy tail)
        int sA0  = kEn;                             // restage buf0
        int sA1  = (2 * j + 3 < NKT) ? 2 * j + 3 : NKT - 1;  // restage buf1
        s16x8 af[8];

        // ---- even body: tile 2j (buf0), consumes bqE ----
#pragma unroll
        for (int n = 0; n < 4; ++n)
            bqO[n] = *(const s16x8*)(bfr + (size_t)kO * 8192 + n * 512);
#pragma unroll
        for (int m = 0; m < 8; ++m) af[m] = *(const s16x8*)&As[0][aoff + m * 512];
        __builtin_amdgcn_s_setprio(1);
#pragma unroll
        for (int m = 0; m < 8; ++m)
#pragma unroll
            for (int n = 0; n < 4; ++n)
                acc[m][n] = __builtin_amdgcn_mfma_f32_16x16x32_bf16(af[m], bqE[n], acc[m][n], 0, 0, 0);
        __builtin_amdgcn_s_setprio(0);
        VMCNT(4);      // A-stage of tile 2j+1 landed (bqO x4 remain in flight)
        BARRIER;       // buf0 reads done chip-wide; buf1 (tile 2j+1) visible
        stageA(0, sA0);

        // ---- odd body: tile 2j+1 (buf1), consumes bqO ----
#pragma unroll
        for (int n = 0; n < 4; ++n)
            bqE[n] = *(const s16x8*)(bfr + (size_t)kEn * 8192 + n * 512);
#pragma unroll
        for (int m = 0; m < 8; ++m) af[m] = *(const s16x8*)&As[1][aoff + m * 512];
        __builtin_amdgcn_s_setprio(1);
#pragma unroll
        for (int m = 0; m < 8; ++m)
#pragma unroll
            for (int n = 0; n < 4; ++n)
                acc[m][n] = __builtin_amdgcn_mfma_f32_16x16x32_bf16(af[m], bqO[n], acc[m][n], 0, 0, 0);
        __builtin_amdgcn_s_setprio(0);
        VMCNT(4);      // A-stage of tile 2j+2 landed (bqE x4 remain in flight)
        BARRIER;       // buf1 reads done; buf0 (tile 2j+2) visible
        stageA(1, sA1);
    }
    VMCNT(0);   // drain dummy stages + dummy bq before LDS dealloc

    // ---- epilogue: spart[R][nt*4+wn] over this wave's 64 d-cols ----
    int b_idx = mt >> 3;
    float Vn[4], Qn[4];
#pragma unroll
    for (int n = 0; n < 4; ++n){
        int D = nt * 256 + wn * 64 + n * 16 + q;
        Vn[n] = V[D];
        Qn[n] = qproj[(size_t)b_idx * HDIM + D];
    }
#pragma unroll
    for (int m = 0; m < 8; ++m){
#pragma unroll
        for (int r = 0; r < 4; ++r){
            float s = 0.f;
#pragma unroll
            for (int n = 0; n < 4; ++n){
                float x = acc[m][n][r] + Qn[n];
                s += Vn[n] * tanh_fast(x);
            }
            s += __shfl_xor(s, 1);
            s += __shfl_xor(s, 2);
            s += __shfl_xor(s, 4);
            s += __shfl_xor(s, 8);
            if (q == 0){
                int R = mt * 256 + wm * 128 + m * 16 + g * 4 + r;
                spart[(size_t)R * 16 + nt * 4 + wn] = s;
            }
        }
    }
}

// ---------------- softmax over S per batch ---------------------------------------
__global__ __launch_bounds__(256) void k_softmax(const float* __restrict__ spart,
                                                 const int* __restrict__ mask,
                                                 float* __restrict__ attn){
    int b = blockIdx.x;
    int tid = threadIdx.x;
    int lane = tid & 63, wv = tid >> 6;
    __shared__ float redmx[4];
    __shared__ float redsm[4];

    float sc[8];
#pragma unroll
    for (int i = 0; i < 8; ++i){
        int s = i * 256 + tid;
        const f32x4* p = (const f32x4*)&spart[(size_t)(b * SEQ + s) * 16];
        f32x4 v0 = p[0], v1 = p[1], v2 = p[2], v3 = p[3];
        float sum = (v0.x + v0.y + v0.z + v0.w) + (v1.x + v1.y + v1.z + v1.w)
                  + (v2.x + v2.y + v2.z + v2.w) + (v3.x + v3.y + v3.z + v3.w);
        sc[i] = (mask[b * SEQ + s] == 0) ? -1e9f : sum;
    }
    float mx = sc[0];
#pragma unroll
    for (int i = 1; i < 8; ++i) mx = fmaxf(mx, sc[i]);
#pragma unroll
    for (int o = 32; o >= 1; o >>= 1) mx = fmaxf(mx, __shfl_xor(mx, o));
    if (lane == 0) redmx[wv] = mx;
    __syncthreads();
    mx = fmaxf(fmaxf(redmx[0], redmx[1]), fmaxf(redmx[2], redmx[3]));

    float ex[8], ssum = 0.f;
#pragma unroll
    for (int i = 0; i < 8; ++i){
        ex[i] = __builtin_amdgcn_exp2f((sc[i] - mx) * 1.4426950408889634f);
        ssum += ex[i];
    }
#pragma unroll
    for (int o = 32; o >= 1; o >>= 1) ssum += __shfl_xor(ssum, o);
    if (lane == 0) redsm[wv] = ssum;
    __syncthreads();
    ssum = redsm[0] + redsm[1] + redsm[2] + redsm[3];
    float inv = 1.0f / ssum;
#pragma unroll
    for (int i = 0; i < 8; ++i)
        attn[(size_t)b * SEQ + i * 256 + tid] = ex[i] * inv;
}

// ---------------- context partials from bf16 keys: cpart[b][32][h] ---------------
__global__ __launch_bounds__(256) void k_ctxpart(const u16* __restrict__ keysbf,
                                                 const float* __restrict__ attn,
                                                 float* __restrict__ cpart){
    int blk = blockIdx.x;                 // 1024 blocks
    int b = blk >> 5, scn = blk & 31;     // 64 rows each
    int t = threadIdx.x;
    f32x4 acc = 0.f;
    const s16x4* kp = (const s16x4*)(keysbf + (size_t)(b * SEQ + scn * 64) * HDIM) + t;
    const float* ap = attn + (size_t)b * SEQ + scn * 64;
#pragma unroll 8
    for (int s = 0; s < 64; ++s){
        float a = ap[s];
        s16x4 kv = kp[(size_t)s * 256];
        f32x4 kf;
        kf.x = __uint_as_float((unsigned)(unsigned short)kv[0] << 16);
        kf.y = __uint_as_float((unsigned)(unsigned short)kv[1] << 16);
        kf.z = __uint_as_float((unsigned)(unsigned short)kv[2] << 16);
        kf.w = __uint_as_float((unsigned)(unsigned short)kv[3] << 16);
        acc += a * kf;
    }
    *(f32x4*)&cpart[(size_t)(b * 32 + scn) * HDIM + t * 4] = acc;
}

__global__ __launch_bounds__(256) void k_ctxred(const float* __restrict__ cpart,
                                                float* __restrict__ ctx){
    int idx = blockIdx.x * 256 + threadIdx.x;   // 128 blocks
    int b = idx >> 10, h = idx & 1023;
    float s = 0.f;
#pragma unroll
    for (int sc = 0; sc < 32; ++sc)
        s += cpart[(size_t)(b * 32 + sc) * HDIM + h];
    ctx[idx] = s;
}

// ---------------- launch ---------------------------------------------------------
extern "C" void kernel_launch(void* const* d_in, const int* in_sizes, int n_in,
                              void* d_out, int out_size, void* d_ws, size_t ws_size,
                              hipStream_t stream){
    (void)in_sizes; (void)n_in; (void)out_size; (void)ws_size;
    const float* query = (const float*)d_in[0];
    const float* keys  = (const float*)d_in[1];
    const int*   mask  = (const int*)d_in[2];
    const float* W1    = (const float*)d_in[3];
    const float* W2    = (const float*)d_in[4];
    const float* V     = (const float*)d_in[5];

    float* ctx_out  = (float*)d_out;            // [32][1024]
    float* attn_out = ctx_out + BATCH * HDIM;   // [32][2048]

    char* ws = (char*)d_ws;
    u16*   W1T   = (u16*)ws;                                   // 2 MB @ 0
    u16*   W1F   = (u16*)(ws + (2u << 20));                    // 2 MB @ 2M
    float* qproj = (float*)(ws + (4u << 20));                  // 128 KB @ 4M
    float* spart = (float*)(ws + (4u << 20) + (128u << 10));   // 4 MB
    float* cpart = spart;   // ctxpart partials reuse spart (dead after softmax)
    u16*   keysbf= (u16*)(ws + (9u << 20));                    // 128 MB @ 9M

    k_w1t    <<<dim3(256),  dim3(256), 0, stream>>>(W1, W1T);
    k_w1f    <<<dim3(512),  dim3(256), 0, stream>>>(W1T, W1F);
    k_qproj  <<<dim3(512),  dim3(256), 0, stream>>>(query, W2, qproj);
    k_cvt    <<<dim3(2048), dim3(256), 0, stream>>>(keys, keysbf);
    k_score  <<<dim3(1024), dim3(512), 0, stream>>>(keysbf, W1F, qproj, V, spart);
    k_softmax<<<dim3(32),   dim3(256), 0, stream>>>(spart, mask, attn_out);
    k_ctxpart<<<dim3(1024), dim3(256), 0, stream>>>(keysbf, attn_out, cpart);
    k_ctxred <<<dim3(128),  dim3(256), 0, stream>>>(cpart, ctx_out);
}